// Round 1
// baseline (1413.371 us; speedup 1.0000x reference)
//
#include <hip/hip_runtime.h>

// ---------------------------------------------------------------------------
// InvariantPolynomial: e3nn-style 2-layer fully-connected tensor product GNN.
//
// Key simplifications vs reference:
//  * edge_attr = 4 * one_hot(q,16) (x) sh  -> all paths index weights by q.
//  * W3J tensors hard-coded as sparse bilinear forms (derived from the
//    reference's CG + U-matrix construction; signs verified element-wise).
//  * TP1 accumulation via per-(dst,q) aggregation of the 51-dim geometric
//    vector g (51 atomics/edge instead of 368).
//  * TP2 output is l=0 only; last two segment-sums fused into per-graph
//    atomics out[batch[dst]].
//
// ws layout (floats):
//   node_sh : [0,        180000)            20000 x 9
//   G       : [180000,   16500000)          20000 x 16 x 51
//   node_mid: [16500000, 23860000)          20000 x 368   (~95.5 MB total)
// ---------------------------------------------------------------------------

#define N_EDGES   320000
#define NN_NODES  20000
#define NN_GRAPHS 5000

#define WS_NSH_OFF 0
#define WS_G_OFF   180000
#define WS_MID_OFF 16500000
#define ZERO_FLOATS 16500000   // node_sh + G must be zeroed

__device__ __forceinline__ void sh_from_vec(float x, float y, float z,
                                            float* B1, float* B2) {
    const float s3   = 1.7320508075688772f;   // sqrt(3)
    const float s15  = 3.8729833462074170f;   // sqrt(15)
    const float s5h  = 1.1180339887498949f;   // 0.5*sqrt(5)
    const float s15h = 1.9364916731037085f;   // 0.5*sqrt(15)
    B1[0] = s3 * y; B1[1] = s3 * z; B1[2] = s3 * x;
    float r2 = x * x + y * y + z * z;
    B2[0] = s15 * x * y;
    B2[1] = s15 * y * z;
    B2[2] = s5h * (3.f * z * z - r2);
    B2[3] = s15 * x * z;
    B2[4] = s15h * (x * x - y * y);
}

// --------------------------- K0: zero init --------------------------------
__global__ __launch_bounds__(256) void k0_zero(float* __restrict__ ws,
                                               float* __restrict__ out) {
    int tid = blockIdx.x * blockDim.x + threadIdx.x;
    int stride = gridDim.x * blockDim.x;
    float4* w4 = (float4*)ws;
    const int n4 = ZERO_FLOATS / 4;           // 4,125,000
    float4 zv = make_float4(0.f, 0.f, 0.f, 0.f);
    for (int i = tid; i < n4; i += stride) w4[i] = zv;
    float4* o4 = (float4*)out;
    const int m4 = (NN_GRAPHS * 7) / 4;       // 8750
    for (int i = tid; i < m4; i += stride) o4[i] = zv;
}

// ------------------ K1: scatter sh into node_sh[dst] ----------------------
__global__ __launch_bounds__(256) void k1_node_sh(
        const float* __restrict__ pos,
        const int* __restrict__ esrc, const int* __restrict__ edst,
        float* __restrict__ node_sh) {
    int e = blockIdx.x * blockDim.x + threadIdx.x;
    if (e >= N_EDGES) return;
    int s = esrc[e], d = edst[e];
    float x = pos[3 * s + 0] - pos[3 * d + 0];
    float y = pos[3 * s + 1] - pos[3 * d + 1];
    float z = pos[3 * s + 2] - pos[3 * d + 2];
    float B1[3], B2[5];
    sh_from_vec(x, y, z, B1, B2);
    float* row = node_sh + d * 9;
    atomicAdd(row + 0, 1.0f);
    atomicAdd(row + 1, B1[0]);
    atomicAdd(row + 2, B1[1]);
    atomicAdd(row + 3, B1[2]);
    atomicAdd(row + 4, B2[0]);
    atomicAdd(row + 5, B2[1]);
    atomicAdd(row + 6, B2[2]);
    atomicAdd(row + 7, B2[3]);
    atomicAdd(row + 8, B2[4]);
}

// ------- K2: per-edge geometric vector g[51], scatter into G[dst][q] ------
__global__ __launch_bounds__(256) void k2_g(
        const float* __restrict__ pos, const int* __restrict__ zarr,
        const int* __restrict__ esrc, const int* __restrict__ edst,
        const float* __restrict__ node_sh, float* __restrict__ G) {
    int e = blockIdx.x * blockDim.x + threadIdx.x;
    if (e >= N_EDGES) return;
    int s = esrc[e], d = edst[e];
    int q = 4 * zarr[s] + zarr[d];
    float x = pos[3 * s + 0] - pos[3 * d + 0];
    float y = pos[3 * s + 1] - pos[3 * d + 1];
    float z = pos[3 * s + 2] - pos[3 * d + 2];
    float B1[3], B2[5];
    sh_from_vec(x, y, z, B1, B2);

    const float inv_nn = 0.57735026918962576f;
    const float* nr = node_sh + s * 9;
    float a0 = nr[0] * inv_nn;
    float A1[3] = {nr[1] * inv_nn, nr[2] * inv_nn, nr[3] * inv_nn};
    float A2[5] = {nr[4] * inv_nn, nr[5] * inv_nn, nr[6] * inv_nn,
                   nr[7] * inv_nn, nr[8] * inv_nn};

    const float r3  = 0.57735026918962576f;  // 1/sqrt(3)
    const float r5  = 0.44721359549995794f;  // 1/sqrt(5)
    const float r6  = 0.40824829046386302f;  // 1/sqrt(6)
    const float r10 = 0.31622776601683794f;  // 1/sqrt(10)
    const float s30 = 0.18257418583505536f;  // 1/sqrt(30)
    const float rt3 = 1.7320508075688772f;   // sqrt(3)
    const float c222 = 0.58554004376911990f; // sqrt(12/35)
    const float q6 = 0.40824829046386302f;   // 1/sqrt(6)
    const float h6 = 0.20412414523193151f;   // 1/(2 sqrt(6))
    const float h2 = 0.35355339059327376f;   // 1/(2 sqrt(2))
    const float r2c = 0.70710678118654752f;  // 1/sqrt(2)

    float g[51];
    // P0 (0,0,0): C=1
    g[0] = a0;
    // P1 (0,1,2): C = delta/sqrt3
    g[1] = a0 * B1[0] * r3;
    g[2] = a0 * B1[1] * r3;
    g[3] = a0 * B1[2] * r3;
    // P2 (0,2,3): C = delta/sqrt5
    g[4] = a0 * B2[0] * r5;
    g[5] = a0 * B2[1] * r5;
    g[6] = a0 * B2[2] * r5;
    g[7] = a0 * B2[3] * r5;
    g[8] = a0 * B2[4] * r5;
    // P3 (1,0,2): C = delta/sqrt3 (b0 = 1)
    g[9]  = A1[0] * r3;
    g[10] = A1[1] * r3;
    g[11] = A1[2] * r3;
    // P4 (1,1,0): C = -delta/sqrt3
    g[12] = -r3 * (A1[0] * B1[0] + A1[1] * B1[1] + A1[2] * B1[2]);
    // P5 (1,1,1): C = -eps/sqrt6
    g[13] = -r6 * (A1[1] * B1[2] - A1[2] * B1[1]);
    g[14] = -r6 * (A1[2] * B1[0] - A1[0] * B1[2]);
    g[15] = -r6 * (A1[0] * B1[1] - A1[1] * B1[0]);
    // P6 (1,1,3): C = +M_k/sqrt5 (sym traceless basis)
    g[16] = r10 * (A1[0] * B1[2] + A1[2] * B1[0]);
    g[17] = r10 * (A1[0] * B1[1] + A1[1] * B1[0]);
    g[18] = s30 * (2.f * A1[1] * B1[1] - A1[0] * B1[0] - A1[2] * B1[2]);
    g[19] = r10 * (A1[1] * B1[2] + A1[2] * B1[1]);
    g[20] = r10 * (A1[2] * B1[2] - A1[0] * B1[0]);
    // P7 (1,2,2) [l=(1,2,1)]: C = -M_j[i,k]/sqrt5
    {
        float Byy = -B2[2] * q6 - B2[4] * r2c;
        float Bzz = 2.f * B2[2] * q6;
        float Bxx = -B2[2] * q6 + B2[4] * r2c;
        float Bxy = B2[0] * r2c;
        float Byz = B2[1] * r2c;
        float Bxz = B2[3] * r2c;
        g[21] = -r5 * (Byy * A1[0] + Byz * A1[1] + Bxy * A1[2]);
        g[22] = -r5 * (Byz * A1[0] + Bzz * A1[1] + Bxz * A1[2]);
        g[23] = -r5 * (Bxy * A1[0] + Bxz * A1[1] + Bxx * A1[2]);
    }
    // P8 (1,2,4) [l=(1,2,2)]: C = -S[j,i,k]/sqrt30
    g[24] = -s30 * (B2[1] * A1[0] - B2[3] * A1[2] + 2.f * B2[4] * A1[1]);
    g[25] = -s30 * (-B2[0] * A1[0] - rt3 * B2[2] * A1[2] + B2[3] * A1[1] - B2[4] * A1[2]);
    g[26] = -s30 * (rt3 * B2[1] * A1[2] - rt3 * B2[3] * A1[0]);
    g[27] = -s30 * (B2[0] * A1[2] - B2[1] * A1[1] + rt3 * B2[2] * A1[0] - B2[4] * A1[0]);
    g[28] = -s30 * (-2.f * B2[0] * A1[1] + B2[1] * A1[2] + B2[3] * A1[0]);
    // P9 (2,0,3): C = delta/sqrt5
    g[29] = A2[0] * r5;
    g[30] = A2[1] * r5;
    g[31] = A2[2] * r5;
    g[32] = A2[3] * r5;
    g[33] = A2[4] * r5;
    // P10 (2,1,2) [l=(2,1,1)]: C = -M_i[j,k]/sqrt5
    {
        float Ayy = -A2[2] * q6 - A2[4] * r2c;
        float Azz = 2.f * A2[2] * q6;
        float Axx = -A2[2] * q6 + A2[4] * r2c;
        float Axy = A2[0] * r2c;
        float Ayz = A2[1] * r2c;
        float Axz = A2[3] * r2c;
        g[34] = -r5 * (Ayy * B1[0] + Ayz * B1[1] + Axy * B1[2]);
        g[35] = -r5 * (Ayz * B1[0] + Azz * B1[1] + Axz * B1[2]);
        g[36] = -r5 * (Axy * B1[0] + Axz * B1[1] + Axx * B1[2]);
    }
    // P11 (2,1,4) [l=(2,1,2)]: C = +S[i,j,k]/sqrt30
    g[37] = s30 * (A2[1] * B1[0] - A2[3] * B1[2] + 2.f * A2[4] * B1[1]);
    g[38] = s30 * (-A2[0] * B1[0] - rt3 * A2[2] * B1[2] + A2[3] * B1[1] - A2[4] * B1[2]);
    g[39] = s30 * (rt3 * A2[1] * B1[2] - rt3 * A2[3] * B1[0]);
    g[40] = s30 * (A2[0] * B1[2] - A2[1] * B1[1] + rt3 * A2[2] * B1[0] - A2[4] * B1[0]);
    g[41] = s30 * (-2.f * A2[0] * B1[1] + A2[1] * B1[2] + A2[3] * B1[0]);
    // P12 (2,2,0): C = +delta/sqrt5
    g[42] = r5 * (A2[0] * B2[0] + A2[1] * B2[1] + A2[2] * B2[2] +
                  A2[3] * B2[3] + A2[4] * B2[4]);
    // P13 (2,2,1): C = +S[i,k,j]/sqrt30
    g[43] = s30 * (-A2[0] * B2[1] + A2[1] * B2[0] +
                   rt3 * (A2[2] * B2[3] - A2[3] * B2[2]) +
                   A2[3] * B2[4] - A2[4] * B2[3]);
    g[44] = s30 * (-2.f * A2[0] * B2[4] + 2.f * A2[4] * B2[0] -
                   A2[1] * B2[3] + A2[3] * B2[1]);
    g[45] = s30 * (A2[0] * B2[3] - A2[3] * B2[0] +
                   rt3 * (A2[1] * B2[2] - A2[2] * B2[1]) +
                   A2[1] * B2[4] - A2[4] * B2[1]);
    // P14 (2,2,3) [l=(2,2,2)]: C = -Tr(MMM)*sqrt(12/35)
    g[46] = -c222 * (-q6 * (A2[0] * B2[2] + A2[2] * B2[0]) +
                     h2 * (A2[1] * B2[3] + A2[3] * B2[1]));
    g[47] = -c222 * (h6 * (A2[1] * B2[2] + A2[2] * B2[1]) -
                     h2 * (A2[1] * B2[4] + A2[4] * B2[1]) +
                     h2 * (A2[0] * B2[3] + A2[3] * B2[0]));
    g[48] = -c222 * (q6 * (A2[2] * B2[2] - A2[0] * B2[0] - A2[4] * B2[4]) +
                     h6 * (A2[1] * B2[1] + A2[3] * B2[3]));
    g[49] = -c222 * (h6 * (A2[3] * B2[2] + A2[2] * B2[3]) +
                     h2 * (A2[3] * B2[4] + A2[4] * B2[3]) +
                     h2 * (A2[0] * B2[1] + A2[1] * B2[0]));
    g[50] = -c222 * (-q6 * (A2[4] * B2[2] + A2[2] * B2[4]) +
                     h2 * (A2[3] * B2[3] - A2[1] * B2[1]));

    float* gr = G + (size_t)(d * 16 + q) * 51;
#pragma unroll
    for (int i = 0; i < 51; i++) atomicAdd(gr + i, g[i]);
}

// ------------- K3: node_mid[n] = alpha * W1[q] . G[n][q] ------------------
__global__ __launch_bounds__(384) void k3_mid(
        const float* __restrict__ G, const float* __restrict__ w1,
        float* __restrict__ mid) {
    __shared__ float lw[6912];
    for (int i = threadIdx.x; i < 6912; i += 384) lw[i] = w1[i];
    __syncthreads();
    int n = blockIdx.x;
    int j = threadIdx.x;
    if (j >= 368) return;
    const float* Gn = G + (size_t)n * 816;  // 16*51
    float acc = 0.f;
    float res = 0.f;
    if (j < 64) {  // c0: 64 scalars.  paths P0(off 0), P4(2048), P12(5248)
        int w = j;
        for (int q = 0; q < 16; q++) {
            const float* gq = Gn + q * 51;
            acc += gq[0]  * lw[q * 64 + w]
                 + gq[12] * lw[2048 + q * 64 + w]
                 + gq[42] * lw[5248 + q * 64 + w];
        }
        res = 0.33333333333333333f * acc;           // alpha0*4*inv_nn
    } else if (j < 136) {  // c1: 24x3. P5(3072), P13(6272)
        int t = j - 64, w = t / 3, k = t - 3 * w;
        for (int q = 0; q < 16; q++) {
            const float* gq = Gn + q * 51;
            acc += gq[13 + k] * lw[3072 + q * 24 + w]
                 + gq[43 + k] * lw[6272 + q * 24 + w];
        }
        res = 0.70710678118654752f * acc;           // alpha1*4*inv_nn
    } else if (j < 208) {  // c2: 24x3. P1(1024), P3(1664), P7(3712), P10(4608)
        int t = j - 136, w = t / 3, k = t - 3 * w;
        for (int q = 0; q < 16; q++) {
            const float* gq = Gn + q * 51;
            acc += gq[1 + k]  * lw[1024 + q * 24 + w]
                 + gq[9 + k]  * lw[1664 + q * 24 + w]
                 + gq[21 + k] * lw[3712 + q * 24 + w]
                 + gq[34 + k] * lw[4608 + q * 24 + w];
        }
        res = 0.5f * acc;                           // alpha2*4*inv_nn
    } else if (j < 288) {  // c3: 16x5. P2(1408), P6(3456), P9(4352), P14(6656)
        int t = j - 208, w = t / 5, k = t - 5 * w;
        for (int q = 0; q < 16; q++) {
            const float* gq = Gn + q * 51;
            acc += gq[4 + k]  * lw[1408 + q * 16 + w]
                 + gq[16 + k] * lw[3456 + q * 16 + w]
                 + gq[29 + k] * lw[4352 + q * 16 + w]
                 + gq[46 + k] * lw[6656 + q * 16 + w];
        }
        res = 0.64549722436790280f * acc;           // alpha3*4*inv_nn
    } else {  // c4: 16x5. P8(4096), P11(4992)
        int t = j - 288, w = t / 5, k = t - 5 * w;
        for (int q = 0; q < 16; q++) {
            const float* gq = Gn + q * 51;
            acc += gq[24 + k] * lw[4096 + q * 16 + w]
                 + gq[37 + k] * lw[4992 + q * 16 + w];
        }
        res = 0.91287092917527690f * acc;           // alpha4*4*inv_nn
    }
    mid[(size_t)n * 368 + j] = res;
}

// --------- K4: TP2 per edge + fused node/graph segment sums ---------------
__global__ __launch_bounds__(256) void k4_out(
        const float* __restrict__ pos, const int* __restrict__ zarr,
        const int* __restrict__ batch,
        const int* __restrict__ esrc, const int* __restrict__ edst,
        const float* __restrict__ mid, const float* __restrict__ w2,
        float* __restrict__ out) {
    __shared__ float lw2[10624];
    for (int i = threadIdx.x; i < 10624; i += 256) lw2[i] = w2[i];
    __syncthreads();
    int e = blockIdx.x * blockDim.x + threadIdx.x;
    if (e >= N_EDGES) return;
    int s = esrc[e], d = edst[e];
    int q = 4 * zarr[s] + zarr[d];
    float x = pos[3 * s + 0] - pos[3 * d + 0];
    float y = pos[3 * s + 1] - pos[3 * d + 1];
    float z = pos[3 * s + 2] - pos[3 * d + 2];
    float B1[3], B2[5];
    sh_from_vec(x, y, z, B1, B2);

    const float* mrow = mid + (size_t)s * 368;

    // T0: (mid0, l=0 attr) -> 6ch.  W2[(u*16+q)*6 + w], off 0
    float S0[6] = {0.f, 0.f, 0.f, 0.f, 0.f, 0.f};
    {
        const float4* m4p = (const float4*)mrow;
#pragma unroll 4
        for (int u4 = 0; u4 < 16; u4++) {
            float4 mv = m4p[u4];
            float mvals[4] = {mv.x, mv.y, mv.z, mv.w};
#pragma unroll
            for (int c = 0; c < 4; c++) {
                int u = u4 * 4 + c;
                const float* wp = lw2 + (u * 16 + q) * 6;
                float m = mvals[c];
#pragma unroll
                for (int w = 0; w < 6; w++) S0[w] += m * wp[w];
            }
        }
    }
    // T1: (mid1 . sh1) -> 1ch (parity -). off 6144
    float S1 = 0.f;
    {
        const float* r = mrow + 64;
#pragma unroll 8
        for (int u = 0; u < 24; u++) {
            float dd = r[3 * u] * B1[0] + r[3 * u + 1] * B1[1] + r[3 * u + 2] * B1[2];
            S1 += dd * lw2[6144 + u * 16 + q];
        }
    }
    // T2: (mid2 . sh1) -> 6ch. off 6528
    float S2[6] = {0.f, 0.f, 0.f, 0.f, 0.f, 0.f};
    {
        const float* r = mrow + 136;
#pragma unroll 8
        for (int u = 0; u < 24; u++) {
            float dd = r[3 * u] * B1[0] + r[3 * u + 1] * B1[1] + r[3 * u + 2] * B1[2];
            const float* wp = lw2 + 6528 + (u * 16 + q) * 6;
#pragma unroll
            for (int w = 0; w < 6; w++) S2[w] += dd * wp[w];
        }
    }
    // T3: (mid3 . sh2) -> 6ch. off 8832
    float S3[6] = {0.f, 0.f, 0.f, 0.f, 0.f, 0.f};
    {
        const float* r = mrow + 208;
#pragma unroll 4
        for (int u = 0; u < 16; u++) {
            float dd = r[5 * u] * B2[0] + r[5 * u + 1] * B2[1] + r[5 * u + 2] * B2[2] +
                       r[5 * u + 3] * B2[3] + r[5 * u + 4] * B2[4];
            const float* wp = lw2 + 8832 + (u * 16 + q) * 6;
#pragma unroll
            for (int w = 0; w < 6; w++) S3[w] += dd * wp[w];
        }
    }
    // T4: (mid4 . sh2) -> 1ch (parity -). off 10368
    float S4 = 0.f;
    {
        const float* r = mrow + 288;
#pragma unroll 4
        for (int u = 0; u < 16; u++) {
            float dd = r[5 * u] * B2[0] + r[5 * u + 1] * B2[1] + r[5 * u + 2] * B2[2] +
                       r[5 * u + 3] * B2[3] + r[5 * u + 4] * B2[4];
            S4 += dd * lw2[10368 + u * 16 + q];
        }
    }

    // Folded coefficients: alpha*4 * C-factor * (0.5*inv_nn final scale)
    const float cT0f =  0.02830690f;   // 4/sqrt(1664)        * 0.5/sqrt3
    const float cT1f = -0.02635231f;   // 4/sqrt(640)*(-1/sq3) * 0.5/sqrt3
    const float cT2f = -0.01634300f;   // 4/sqrt(1664)*(-1/sq3)* 0.5/sqrt3
    const float cT3f =  0.01265893f;   // 4/sqrt(1664)*(1/sq5) * 0.5/sqrt3
    const float cT4f =  0.02041241f;   // 4/sqrt(640)*(1/sq5)  * 0.5/sqrt3

    int gidx = batch[d];
    float* og = out + gidx * 7;
    atomicAdd(og + 0, cT1f * S1 + cT4f * S4);
#pragma unroll
    for (int w = 0; w < 6; w++)
        atomicAdd(og + 1 + w, cT0f * S0[w] + cT2f * S2[w] + cT3f * S3[w]);
}

// ---------------------------------------------------------------------------
extern "C" void kernel_launch(void* const* d_in, const int* in_sizes, int n_in,
                              void* d_out, int out_size, void* d_ws, size_t ws_size,
                              hipStream_t stream) {
    const float* pos  = (const float*)d_in[0];
    const int*   z    = (const int*)d_in[1];
    const int*   bat  = (const int*)d_in[2];
    const int*   esrc = (const int*)d_in[3];
    const int*   edst = (const int*)d_in[4];
    const float* w1   = (const float*)d_in[5];
    const float* w2   = (const float*)d_in[6];
    float* out = (float*)d_out;
    float* ws  = (float*)d_ws;

    float* node_sh = ws + WS_NSH_OFF;
    float* G       = ws + WS_G_OFF;
    float* mid     = ws + WS_MID_OFF;

    k0_zero<<<2048, 256, 0, stream>>>(ws, out);
    k1_node_sh<<<(N_EDGES + 255) / 256, 256, 0, stream>>>(pos, esrc, edst, node_sh);
    k2_g<<<(N_EDGES + 255) / 256, 256, 0, stream>>>(pos, z, esrc, edst, node_sh, G);
    k3_mid<<<NN_NODES, 384, 0, stream>>>(G, w1, mid);
    k4_out<<<(N_EDGES + 255) / 256, 256, 0, stream>>>(pos, z, bat, esrc, edst, mid, w2, out);
}

// Round 2
// 548.814 us; speedup vs baseline: 2.5753x; 2.5753x over previous
//
#include <hip/hip_runtime.h>

// ---------------------------------------------------------------------------
// InvariantPolynomial, round 2: CSR-by-dst + gather everywhere.
//
//  * k_zero   : zero counts + out
//  * k_hist   : counts[dst]++                       (320K int atomics)
//  * k_scan   : exclusive prefix sum (1 block)      -> start[20001], cursor
//  * k_fill   : csr[p] = src | (q<<16)              (320K int atomics)
//  * k_nodesh : wave/node gather sh  -> node_sh     (no atomics, inv_nn folded)
//  * k_mid    : fused TP1: per-node G[16][51] in LDS (ds atomics) -> W1 -> mid
//  * k_out    : fused TP2: wave/node, per-lane u-slot partials over edges,
//               butterfly reduce, 7 global atomics per NODE into out[batch]
//
// ws layout (ints/floats):
//   counts  @ int   [0      , 20000)
//   start   @ int   [32768  , 52769)
//   cursor  @ int   [65536  , 85536)
//   csr     @ int   [98304  , 418304)
//   node_sh @ float [524288 , 704288)     20000 x 9   (pre-scaled by inv_nn)
//   mid     @ float [1048576, 8408576)    20000 x 368
// ---------------------------------------------------------------------------

#define N_EDGES   320000
#define NN_NODES  20000
#define NN_GRAPHS 5000

__device__ __forceinline__ void sh_from_vec(float x, float y, float z,
                                            float* B1, float* B2) {
    const float s3   = 1.7320508075688772f;
    const float s15  = 3.8729833462074170f;
    const float s5h  = 1.1180339887498949f;
    const float s15h = 1.9364916731037085f;
    B1[0] = s3 * y; B1[1] = s3 * z; B1[2] = s3 * x;
    float r2 = x * x + y * y + z * z;
    B2[0] = s15 * x * y;
    B2[1] = s15 * y * z;
    B2[2] = s5h * (3.f * z * z - r2);
    B2[3] = s15 * x * z;
    B2[4] = s15h * (x * x - y * y);
}

// --------------------------- zero ------------------------------------------
__global__ __launch_bounds__(256) void k_zero(int* __restrict__ counts,
                                              float* __restrict__ out) {
    int tid = blockIdx.x * blockDim.x + threadIdx.x;
    int stride = gridDim.x * blockDim.x;
    for (int i = tid; i < NN_NODES; i += stride) counts[i] = 0;
    for (int i = tid; i < NN_GRAPHS * 7; i += stride) out[i] = 0.f;
}

// --------------------------- histogram -------------------------------------
__global__ __launch_bounds__(256) void k_hist(const int* __restrict__ edst,
                                              int* __restrict__ counts) {
    int e = blockIdx.x * blockDim.x + threadIdx.x;
    if (e < N_EDGES) atomicAdd(&counts[edst[e]], 1);
}

// --------------------------- exclusive scan (1 block of 1024) --------------
__global__ __launch_bounds__(1024) void k_scan(const int* __restrict__ counts,
                                               int* __restrict__ start,
                                               int* __restrict__ cursor) {
    __shared__ int sdata[1024];
    __shared__ int carry;
    int tid = threadIdx.x;
    if (tid == 0) carry = 0;
    __syncthreads();
    for (int base = 0; base < NN_NODES; base += 1024) {
        int i = base + tid;
        int v = (i < NN_NODES) ? counts[i] : 0;
        sdata[tid] = v;
        __syncthreads();
        for (int off = 1; off < 1024; off <<= 1) {
            int t = (tid >= off) ? sdata[tid - off] : 0;
            __syncthreads();
            sdata[tid] += t;
            __syncthreads();
        }
        int incl = sdata[tid];
        int c = carry;
        if (i < NN_NODES) {
            int excl = c + incl - v;
            start[i] = excl;
            cursor[i] = excl;
        }
        __syncthreads();
        if (tid == 0) carry = c + sdata[1023];
        __syncthreads();
    }
    if (tid == 0) start[NN_NODES] = carry;   // = N_EDGES
}

// --------------------------- CSR fill --------------------------------------
__global__ __launch_bounds__(256) void k_fill(const int* __restrict__ esrc,
                                              const int* __restrict__ edst,
                                              const int* __restrict__ zarr,
                                              int* __restrict__ cursor,
                                              int* __restrict__ csr) {
    int e = blockIdx.x * blockDim.x + threadIdx.x;
    if (e >= N_EDGES) return;
    int d = edst[e];
    int s = esrc[e];
    int q = 4 * zarr[s] + zarr[d];
    int p = atomicAdd(&cursor[d], 1);
    csr[p] = s | (q << 16);
}

// --------------------------- node_sh gather (wave per node) ----------------
__global__ __launch_bounds__(256) void k_nodesh(const float* __restrict__ pos,
                                                const int* __restrict__ start,
                                                const int* __restrict__ csr,
                                                float* __restrict__ node_sh) {
    int wave = threadIdx.x >> 6;
    int lane = threadIdx.x & 63;
    int n = blockIdx.x * 4 + wave;
    if (n >= NN_NODES) return;
    float pdx = pos[3 * n], pdy = pos[3 * n + 1], pdz = pos[3 * n + 2];
    int s0 = start[n], s1 = start[n + 1];
    float acc[9] = {0.f, 0.f, 0.f, 0.f, 0.f, 0.f, 0.f, 0.f, 0.f};
    for (int idx = s0 + lane; idx < s1; idx += 64) {
        int s = csr[idx] & 0xFFFF;
        float x = pos[3 * s] - pdx;
        float y = pos[3 * s + 1] - pdy;
        float z = pos[3 * s + 2] - pdz;
        float B1[3], B2[5];
        sh_from_vec(x, y, z, B1, B2);
        acc[0] += 1.f;
        acc[1] += B1[0]; acc[2] += B1[1]; acc[3] += B1[2];
        acc[4] += B2[0]; acc[5] += B2[1]; acc[6] += B2[2];
        acc[7] += B2[3]; acc[8] += B2[4];
    }
#pragma unroll
    for (int off = 32; off > 0; off >>= 1)
#pragma unroll
        for (int i = 0; i < 9; i++) acc[i] += __shfl_down(acc[i], off, 64);
    if (lane == 0) {
        const float inv_nn = 0.57735026918962576f;
#pragma unroll
        for (int i = 0; i < 9; i++) node_sh[n * 9 + i] = acc[i] * inv_nn;
    }
}

// --------------- fused TP1: G in LDS -> W1 contraction -> mid --------------
__global__ __launch_bounds__(384) void k_mid(const float* __restrict__ pos,
                                             const float* __restrict__ node_sh,
                                             const int* __restrict__ start,
                                             const int* __restrict__ csr,
                                             const float* __restrict__ w1,
                                             float* __restrict__ mid) {
    __shared__ float lw[6912];
    __shared__ float Gl[8 * 816];
    int t = threadIdx.x;
    for (int i = t; i < 6912; i += 384) lw[i] = w1[i];
    for (int i = t; i < 8 * 816; i += 384) Gl[i] = 0.f;
    __syncthreads();

    int r = t / 48;
    int slot = t - 48 * r;
    int n = blockIdx.x * 8 + r;
    float pdx = pos[3 * n], pdy = pos[3 * n + 1], pdz = pos[3 * n + 2];
    int s0 = start[n], s1 = start[n + 1];
    float* Gb = Gl + r * 816;

    const float r3  = 0.57735026918962576f;
    const float r5  = 0.44721359549995794f;
    const float r6  = 0.40824829046386302f;
    const float r10 = 0.31622776601683794f;
    const float s30 = 0.18257418583505536f;
    const float rt3 = 1.7320508075688772f;
    const float c222 = 0.58554004376911990f;
    const float q6 = 0.40824829046386302f;
    const float h6 = 0.20412414523193151f;
    const float h2 = 0.35355339059327376f;
    const float r2c = 0.70710678118654752f;

    for (int idx = s0 + slot; idx < s1; idx += 48) {
        int pk = csr[idx];
        int s = pk & 0xFFFF;
        int q = pk >> 16;
        float x = pos[3 * s] - pdx;
        float y = pos[3 * s + 1] - pdy;
        float z = pos[3 * s + 2] - pdz;
        float B1[3], B2[5];
        sh_from_vec(x, y, z, B1, B2);
        const float* nr = node_sh + s * 9;      // pre-scaled by inv_nn
        float a0 = nr[0];
        float A1[3] = {nr[1], nr[2], nr[3]};
        float A2[5] = {nr[4], nr[5], nr[6], nr[7], nr[8]};
        float* gr = Gb + q * 51;

        atomicAdd(gr + 0, a0);
        atomicAdd(gr + 1, a0 * B1[0] * r3);
        atomicAdd(gr + 2, a0 * B1[1] * r3);
        atomicAdd(gr + 3, a0 * B1[2] * r3);
        atomicAdd(gr + 4, a0 * B2[0] * r5);
        atomicAdd(gr + 5, a0 * B2[1] * r5);
        atomicAdd(gr + 6, a0 * B2[2] * r5);
        atomicAdd(gr + 7, a0 * B2[3] * r5);
        atomicAdd(gr + 8, a0 * B2[4] * r5);
        atomicAdd(gr + 9,  A1[0] * r3);
        atomicAdd(gr + 10, A1[1] * r3);
        atomicAdd(gr + 11, A1[2] * r3);
        atomicAdd(gr + 12, -r3 * (A1[0] * B1[0] + A1[1] * B1[1] + A1[2] * B1[2]));
        atomicAdd(gr + 13, -r6 * (A1[1] * B1[2] - A1[2] * B1[1]));
        atomicAdd(gr + 14, -r6 * (A1[2] * B1[0] - A1[0] * B1[2]));
        atomicAdd(gr + 15, -r6 * (A1[0] * B1[1] - A1[1] * B1[0]));
        atomicAdd(gr + 16, r10 * (A1[0] * B1[2] + A1[2] * B1[0]));
        atomicAdd(gr + 17, r10 * (A1[0] * B1[1] + A1[1] * B1[0]));
        atomicAdd(gr + 18, s30 * (2.f * A1[1] * B1[1] - A1[0] * B1[0] - A1[2] * B1[2]));
        atomicAdd(gr + 19, r10 * (A1[1] * B1[2] + A1[2] * B1[1]));
        atomicAdd(gr + 20, r10 * (A1[2] * B1[2] - A1[0] * B1[0]));
        {
            float Byy = -B2[2] * q6 - B2[4] * r2c;
            float Bzz = 2.f * B2[2] * q6;
            float Bxx = -B2[2] * q6 + B2[4] * r2c;
            float Bxy = B2[0] * r2c;
            float Byz = B2[1] * r2c;
            float Bxz = B2[3] * r2c;
            atomicAdd(gr + 21, -r5 * (Byy * A1[0] + Byz * A1[1] + Bxy * A1[2]));
            atomicAdd(gr + 22, -r5 * (Byz * A1[0] + Bzz * A1[1] + Bxz * A1[2]));
            atomicAdd(gr + 23, -r5 * (Bxy * A1[0] + Bxz * A1[1] + Bxx * A1[2]));
        }
        atomicAdd(gr + 24, -s30 * (B2[1] * A1[0] - B2[3] * A1[2] + 2.f * B2[4] * A1[1]));
        atomicAdd(gr + 25, -s30 * (-B2[0] * A1[0] - rt3 * B2[2] * A1[2] + B2[3] * A1[1] - B2[4] * A1[2]));
        atomicAdd(gr + 26, -s30 * (rt3 * B2[1] * A1[2] - rt3 * B2[3] * A1[0]));
        atomicAdd(gr + 27, -s30 * (B2[0] * A1[2] - B2[1] * A1[1] + rt3 * B2[2] * A1[0] - B2[4] * A1[0]));
        atomicAdd(gr + 28, -s30 * (-2.f * B2[0] * A1[1] + B2[1] * A1[2] + B2[3] * A1[0]));
        atomicAdd(gr + 29, A2[0] * r5);
        atomicAdd(gr + 30, A2[1] * r5);
        atomicAdd(gr + 31, A2[2] * r5);
        atomicAdd(gr + 32, A2[3] * r5);
        atomicAdd(gr + 33, A2[4] * r5);
        {
            float Ayy = -A2[2] * q6 - A2[4] * r2c;
            float Azz = 2.f * A2[2] * q6;
            float Axx = -A2[2] * q6 + A2[4] * r2c;
            float Axy = A2[0] * r2c;
            float Ayz = A2[1] * r2c;
            float Axz = A2[3] * r2c;
            atomicAdd(gr + 34, -r5 * (Ayy * B1[0] + Ayz * B1[1] + Axy * B1[2]));
            atomicAdd(gr + 35, -r5 * (Ayz * B1[0] + Azz * B1[1] + Axz * B1[2]));
            atomicAdd(gr + 36, -r5 * (Axy * B1[0] + Axz * B1[1] + Axx * B1[2]));
        }
        atomicAdd(gr + 37, s30 * (A2[1] * B1[0] - A2[3] * B1[2] + 2.f * A2[4] * B1[1]));
        atomicAdd(gr + 38, s30 * (-A2[0] * B1[0] - rt3 * A2[2] * B1[2] + A2[3] * B1[1] - A2[4] * B1[2]));
        atomicAdd(gr + 39, s30 * (rt3 * A2[1] * B1[2] - rt3 * A2[3] * B1[0]));
        atomicAdd(gr + 40, s30 * (A2[0] * B1[2] - A2[1] * B1[1] + rt3 * A2[2] * B1[0] - A2[4] * B1[0]));
        atomicAdd(gr + 41, s30 * (-2.f * A2[0] * B1[1] + A2[1] * B1[2] + A2[3] * B1[0]));
        atomicAdd(gr + 42, r5 * (A2[0] * B2[0] + A2[1] * B2[1] + A2[2] * B2[2] +
                                 A2[3] * B2[3] + A2[4] * B2[4]));
        atomicAdd(gr + 43, s30 * (-A2[0] * B2[1] + A2[1] * B2[0] +
                                  rt3 * (A2[2] * B2[3] - A2[3] * B2[2]) +
                                  A2[3] * B2[4] - A2[4] * B2[3]));
        atomicAdd(gr + 44, s30 * (-2.f * A2[0] * B2[4] + 2.f * A2[4] * B2[0] -
                                  A2[1] * B2[3] + A2[3] * B2[1]));
        atomicAdd(gr + 45, s30 * (A2[0] * B2[3] - A2[3] * B2[0] +
                                  rt3 * (A2[1] * B2[2] - A2[2] * B2[1]) +
                                  A2[1] * B2[4] - A2[4] * B2[1]));
        atomicAdd(gr + 46, -c222 * (-q6 * (A2[0] * B2[2] + A2[2] * B2[0]) +
                                    h2 * (A2[1] * B2[3] + A2[3] * B2[1])));
        atomicAdd(gr + 47, -c222 * (h6 * (A2[1] * B2[2] + A2[2] * B2[1]) -
                                    h2 * (A2[1] * B2[4] + A2[4] * B2[1]) +
                                    h2 * (A2[0] * B2[3] + A2[3] * B2[0])));
        atomicAdd(gr + 48, -c222 * (q6 * (A2[2] * B2[2] - A2[0] * B2[0] - A2[4] * B2[4]) +
                                    h6 * (A2[1] * B2[1] + A2[3] * B2[3])));
        atomicAdd(gr + 49, -c222 * (h6 * (A2[3] * B2[2] + A2[2] * B2[3]) +
                                    h2 * (A2[3] * B2[4] + A2[4] * B2[3]) +
                                    h2 * (A2[0] * B2[1] + A2[1] * B2[0])));
        atomicAdd(gr + 50, -c222 * (-q6 * (A2[4] * B2[2] + A2[2] * B2[4]) +
                                    h2 * (A2[3] * B2[3] - A2[1] * B2[1])));
    }
    __syncthreads();

    // Phase 2: per output j, contract with W1 (alpha*4*inv_nn folded).
    int j = t;
    if (j >= 368) return;
    if (j < 64) {
        int w = j;
        for (int r2 = 0; r2 < 8; r2++) {
            const float* Gn = Gl + r2 * 816;
            float acc = 0.f;
            for (int q = 0; q < 16; q++) {
                const float* gq = Gn + q * 51;
                acc += gq[0]  * lw[q * 64 + w]
                     + gq[12] * lw[2048 + q * 64 + w]
                     + gq[42] * lw[5248 + q * 64 + w];
            }
            mid[(size_t)(blockIdx.x * 8 + r2) * 368 + j] = 0.33333333333333333f * acc;
        }
    } else if (j < 136) {
        int tt = j - 64, w = tt / 3, k = tt - 3 * w;
        for (int r2 = 0; r2 < 8; r2++) {
            const float* Gn = Gl + r2 * 816;
            float acc = 0.f;
            for (int q = 0; q < 16; q++) {
                const float* gq = Gn + q * 51;
                acc += gq[13 + k] * lw[3072 + q * 24 + w]
                     + gq[43 + k] * lw[6272 + q * 24 + w];
            }
            mid[(size_t)(blockIdx.x * 8 + r2) * 368 + j] = 0.70710678118654752f * acc;
        }
    } else if (j < 208) {
        int tt = j - 136, w = tt / 3, k = tt - 3 * w;
        for (int r2 = 0; r2 < 8; r2++) {
            const float* Gn = Gl + r2 * 816;
            float acc = 0.f;
            for (int q = 0; q < 16; q++) {
                const float* gq = Gn + q * 51;
                acc += gq[1 + k]  * lw[1024 + q * 24 + w]
                     + gq[9 + k]  * lw[1664 + q * 24 + w]
                     + gq[21 + k] * lw[3712 + q * 24 + w]
                     + gq[34 + k] * lw[4608 + q * 24 + w];
            }
            mid[(size_t)(blockIdx.x * 8 + r2) * 368 + j] = 0.5f * acc;
        }
    } else if (j < 288) {
        int tt = j - 208, w = tt / 5, k = tt - 5 * w;
        for (int r2 = 0; r2 < 8; r2++) {
            const float* Gn = Gl + r2 * 816;
            float acc = 0.f;
            for (int q = 0; q < 16; q++) {
                const float* gq = Gn + q * 51;
                acc += gq[4 + k]  * lw[1408 + q * 16 + w]
                     + gq[16 + k] * lw[3456 + q * 16 + w]
                     + gq[29 + k] * lw[4352 + q * 16 + w]
                     + gq[46 + k] * lw[6656 + q * 16 + w];
            }
            mid[(size_t)(blockIdx.x * 8 + r2) * 368 + j] = 0.64549722436790280f * acc;
        }
    } else {
        int tt = j - 288, w = tt / 5, k = tt - 5 * w;
        for (int r2 = 0; r2 < 8; r2++) {
            const float* Gn = Gl + r2 * 816;
            float acc = 0.f;
            for (int q = 0; q < 16; q++) {
                const float* gq = Gn + q * 51;
                acc += gq[24 + k] * lw[4096 + q * 16 + w]
                     + gq[37 + k] * lw[4992 + q * 16 + w];
            }
            mid[(size_t)(blockIdx.x * 8 + r2) * 368 + j] = 0.91287092917527690f * acc;
        }
    }
}

// --------------- fused TP2 + graph reduce (wave per node) ------------------
__global__ __launch_bounds__(512) void k_out(const float* __restrict__ pos,
                                             const int* __restrict__ batch,
                                             const int* __restrict__ start,
                                             const int* __restrict__ csr,
                                             const float* __restrict__ mid,
                                             const float* __restrict__ w2,
                                             float* __restrict__ out) {
    __shared__ float lw2[10624];
    for (int i = threadIdx.x; i < 10624; i += 512) lw2[i] = w2[i];
    __syncthreads();

    int wave = threadIdx.x >> 6;
    int lane = threadIdx.x & 63;
    int n = blockIdx.x * 8 + wave;
    float pdx = pos[3 * n], pdy = pos[3 * n + 1], pdz = pos[3 * n + 2];
    int s0 = start[n], s1 = start[n + 1];

    // per-lane u-slot partials
    float p0[6] = {0.f, 0.f, 0.f, 0.f, 0.f, 0.f};   // T0, u = lane
    float pA[6] = {0.f, 0.f, 0.f, 0.f, 0.f, 0.f};   // T1/T2/T3 by lane range
    float pB = 0.f;                                  // T4, lanes 0..15

    for (int idx = s0; idx < s1; ++idx) {
        int pk = csr[idx];
        int s = pk & 0xFFFF;
        int q = pk >> 16;
        float x = pos[3 * s] - pdx;
        float y = pos[3 * s + 1] - pdy;
        float z = pos[3 * s + 2] - pdz;
        float B1[3], B2[5];
        sh_from_vec(x, y, z, B1, B2);
        const float* mrow = mid + (size_t)s * 368;

        // T0: u = lane (coalesced 256B)
        {
            float m = mrow[lane];
            const float* wp = lw2 + (lane * 16 + q) * 6;
#pragma unroll
            for (int w = 0; w < 6; w++) p0[w] += m * wp[w];
        }
        // slot2
        if (lane < 24) {            // T1 u=lane
            const float* rp = mrow + 64 + 3 * lane;
            float dd = rp[0] * B1[0] + rp[1] * B1[1] + rp[2] * B1[2];
            pA[0] += dd * lw2[6144 + lane * 16 + q];
        } else if (lane < 48) {     // T2 u=lane-24
            int u = lane - 24;
            const float* rp = mrow + 136 + 3 * u;
            float dd = rp[0] * B1[0] + rp[1] * B1[1] + rp[2] * B1[2];
            const float* wp = lw2 + 6528 + (u * 16 + q) * 6;
#pragma unroll
            for (int w = 0; w < 6; w++) pA[w] += dd * wp[w];
        } else {                    // T3 u=lane-48
            int u = lane - 48;
            const float* rp = mrow + 208 + 5 * u;
            float dd = rp[0] * B2[0] + rp[1] * B2[1] + rp[2] * B2[2] +
                       rp[3] * B2[3] + rp[4] * B2[4];
            const float* wp = lw2 + 8832 + (u * 16 + q) * 6;
#pragma unroll
            for (int w = 0; w < 6; w++) pA[w] += dd * wp[w];
        }
        // T4: lanes 0..15
        if (lane < 16) {
            const float* rp = mrow + 288 + 5 * lane;
            float dd = rp[0] * B2[0] + rp[1] * B2[1] + rp[2] * B2[2] +
                       rp[3] * B2[3] + rp[4] * B2[4];
            pB += dd * lw2[10368 + lane * 16 + q];
        }
    }

    const float cT0f =  0.02830690f;
    const float cT1f = -0.02635231f;
    const float cT2f = -0.01634300f;
    const float cT3f =  0.01265893f;
    const float cT4f =  0.02041241f;

    float o0 = 0.f;
    float ov[6];
#pragma unroll
    for (int w = 0; w < 6; w++) ov[w] = cT0f * p0[w];
    if (lane < 24) {
        o0 += cT1f * pA[0];
    } else if (lane < 48) {
#pragma unroll
        for (int w = 0; w < 6; w++) ov[w] += cT2f * pA[w];
    } else {
#pragma unroll
        for (int w = 0; w < 6; w++) ov[w] += cT3f * pA[w];
    }
    if (lane < 16) o0 += cT4f * pB;

#pragma unroll
    for (int off = 32; off > 0; off >>= 1) {
        o0 += __shfl_down(o0, off, 64);
#pragma unroll
        for (int w = 0; w < 6; w++) ov[w] += __shfl_down(ov[w], off, 64);
    }
    if (lane == 0) {
        float* og = out + batch[n] * 7;
        atomicAdd(og + 0, o0);
#pragma unroll
        for (int w = 0; w < 6; w++) atomicAdd(og + 1 + w, ov[w]);
    }
}

// ---------------------------------------------------------------------------
extern "C" void kernel_launch(void* const* d_in, const int* in_sizes, int n_in,
                              void* d_out, int out_size, void* d_ws, size_t ws_size,
                              hipStream_t stream) {
    const float* pos  = (const float*)d_in[0];
    const int*   z    = (const int*)d_in[1];
    const int*   bat  = (const int*)d_in[2];
    const int*   esrc = (const int*)d_in[3];
    const int*   edst = (const int*)d_in[4];
    const float* w1   = (const float*)d_in[5];
    const float* w2   = (const float*)d_in[6];
    float* out = (float*)d_out;

    int*   wsI = (int*)d_ws;
    float* wsF = (float*)d_ws;
    int* counts = wsI + 0;
    int* start  = wsI + 32768;
    int* cursor = wsI + 65536;
    int* csr    = wsI + 98304;
    float* node_sh = wsF + 524288;
    float* mid     = wsF + 1048576;

    k_zero<<<64, 256, 0, stream>>>(counts, out);
    k_hist<<<(N_EDGES + 255) / 256, 256, 0, stream>>>(edst, counts);
    k_scan<<<1, 1024, 0, stream>>>(counts, start, cursor);
    k_fill<<<(N_EDGES + 255) / 256, 256, 0, stream>>>(esrc, edst, z, cursor, csr);
    k_nodesh<<<NN_NODES / 4, 256, 0, stream>>>(pos, start, csr, node_sh);
    k_mid<<<NN_NODES / 8, 384, 0, stream>>>(pos, node_sh, start, csr, w1, mid);
    k_out<<<NN_NODES / 8, 512, 0, stream>>>(pos, bat, start, csr, mid, w2, out);
}